// Round 1
// 499.107 us; speedup vs baseline: 1.0200x; 1.0200x over previous
//
#include <hip/hip_runtime.h>

#define PH 14
#define PW 14
#define CC 512
#define IW 128
#define C4G (CC / 4)  // 128 float4 channel groups per pixel

typedef float f32x4 __attribute__((ext_vector_type(4)));

// One wave (64 lanes) = one output pixel (roi, py, px).
// Each lane handles 2 float4 channel groups: c4 = lane and lane + 64.
// pid is wave-uniform -> readfirstlane pins it to SGPR so ROI fetch and all
// index math run on the scalar unit; vector side only does loads + lerps.
__global__ __launch_bounds__(256) void roi_pool_kernel(
    const float* __restrict__ img, const int* __restrict__ rois,
    float* __restrict__ out, int npix) {
  int wid = blockIdx.x * 4 + (threadIdx.x >> 6);  // 4 waves per block
  if (wid >= npix) return;                        // wave-uniform branch
  int pid = __builtin_amdgcn_readfirstlane(wid);
  int lane = threadIdx.x & 63;

  int px = pid % PW;
  int tmp = pid / PW;
  int py = tmp % PH;
  int n = tmp / PH;

  // scalar (s_load_dwordx4) ROI fetch
  int x0 = rois[n * 4 + 0];
  int y0 = rois[n * 4 + 1];
  int x1 = rois[n * 4 + 2];
  int y1 = rois[n * 4 + 3];
  int in_w = x1 - x0 + 1;
  int in_h = y1 - y0 + 1;

  // Match reference float op order exactly: scale = in/out, then idx*scale.
  float scale_y = (float)in_h / (float)PH;
  float scale_x = (float)in_w / (float)PW;
  float sy = (float)py * scale_y;
  float sx = (float)px * scale_x;
  int yt = (int)floorf(sy);
  int xt = (int)floorf(sx);
  int yb = min(yt + 1, in_h - 1);
  int xr = min(xt + 1, in_w - 1);
  float wy = sy - (float)yt;
  float wx = sx - (float)xt;

  int rt = y0 + yt, rb = y0 + yb;
  int cl = x0 + xt, cr = x0 + xr;

  const f32x4* __restrict__ imgv = (const f32x4*)img;
  const f32x4* p00 = imgv + (size_t)(rt * IW + cl) * C4G + lane;
  const f32x4* p01 = imgv + (size_t)(rt * IW + cr) * C4G + lane;
  const f32x4* p10 = imgv + (size_t)(rb * IW + cl) * C4G + lane;
  const f32x4* p11 = imgv + (size_t)(rb * IW + cr) * C4G + lane;

  // 8 loads in flight per wave (2x the old MLP)
  f32x4 a00 = p00[0], b00 = p00[64];
  f32x4 a01 = p01[0], b01 = p01[64];
  f32x4 a10 = p10[0], b10 = p10[64];
  f32x4 a11 = p11[0], b11 = p11[64];

  f32x4 wxv = wx;
  f32x4 wyv = wy;

  f32x4 atop = a00 + wxv * (a01 - a00);
  f32x4 abot = a10 + wxv * (a11 - a10);
  f32x4 ra = atop + wyv * (abot - atop);

  f32x4 btop = b00 + wxv * (b01 - b00);
  f32x4 bbot = b10 + wxv * (b11 - b10);
  f32x4 rbv = btop + wyv * (bbot - btop);

  // Output is never re-read: non-temporal stores keep the 401 MB write
  // stream out of L2 so L2 retains image lines for the corner reads.
  f32x4* outv = (f32x4*)out + (size_t)pid * C4G + lane;
  __builtin_nontemporal_store(ra, outv);
  __builtin_nontemporal_store(rbv, outv + 64);
}

extern "C" void kernel_launch(void* const* d_in, const int* in_sizes, int n_in,
                              void* d_out, int out_size, void* d_ws, size_t ws_size,
                              hipStream_t stream) {
  const float* img = (const float*)d_in[0];
  const int* rois = (const int*)d_in[1];
  float* out = (float*)d_out;

  int N = in_sizes[1] / 4;   // rois is [N,4]
  int npix = N * PH * PW;    // output pixels == waves
  int waves_per_block = 4;   // 256 threads
  int blocks = (npix + waves_per_block - 1) / waves_per_block;
  roi_pool_kernel<<<blocks, 256, 0, stream>>>(img, rois, out, npix);
}

// Round 2
// 457.714 us; speedup vs baseline: 1.1122x; 1.0904x over previous
//
#include <hip/hip_runtime.h>

#define PH 14
#define PW 14
#define CC 512
#define IW 128
#define C4G (CC / 4)  // 128 float4 channel groups per pixel

typedef float f32x4 __attribute__((ext_vector_type(4)));

// One wave (64 lanes) = one output pixel (roi, py, px); each lane handles
// 2 float4 channel groups (lane, lane+64). 4 waves/block = 4 px/block,
// 49 blocks per ROI (196 px).
//
// XCD-aware swizzle: the HW round-robins blockIdx across the 8 XCDs, so
// without remapping, blocks that share ROI rows/columns scatter across 8
// private L2s and every reuse is an L3/HBM miss. Remap so all 49 blocks of
// ROI r land on XCD r%8: per-XCD resident window ~5 ROIs (~3 MB footprint)
// fits the 4 MB L2, converting the ~4x intra-ROI corner reuse into L2 hits.
__global__ __launch_bounds__(256) void roi_pool_kernel(
    const float* __restrict__ img, const int* __restrict__ rois,
    float* __restrict__ out, int npix, int swizzle) {
  int w = threadIdx.x >> 6;  // wave within block
  int wid;
  if (swizzle) {
    int bid = blockIdx.x;
    int x   = bid & 7;    // target XCD (HW: XCD = blockIdx % 8)
    int seq = bid >> 3;   // dense sequence within this XCD
    int rg  = seq / 49;   // ROI group index on this XCD
    int k   = seq % 49;   // block within ROI (4 px each)
    int r   = rg * 8 + x; // ROI id: all its blocks stay on XCD x
    wid = r * (PH * PW) + k * 4 + w;
  } else {
    wid = blockIdx.x * 4 + w;
  }
  if (wid >= npix) return;                   // wave-uniform branch
  int pid = __builtin_amdgcn_readfirstlane(wid);
  int lane = threadIdx.x & 63;

  int px = pid % PW;
  int tmp = pid / PW;
  int py = tmp % PH;
  int n = tmp / PH;

  // scalar (s_load_dwordx4) ROI fetch
  int x0 = rois[n * 4 + 0];
  int y0 = rois[n * 4 + 1];
  int x1 = rois[n * 4 + 2];
  int y1 = rois[n * 4 + 3];
  int in_w = x1 - x0 + 1;
  int in_h = y1 - y0 + 1;

  // Match reference float op order exactly: scale = in/out, then idx*scale.
  float scale_y = (float)in_h / (float)PH;
  float scale_x = (float)in_w / (float)PW;
  float sy = (float)py * scale_y;
  float sx = (float)px * scale_x;
  int yt = (int)floorf(sy);
  int xt = (int)floorf(sx);
  int yb = min(yt + 1, in_h - 1);
  int xr = min(xt + 1, in_w - 1);
  float wy = sy - (float)yt;
  float wx = sx - (float)xt;

  int rt = y0 + yt, rb = y0 + yb;
  int cl = x0 + xt, cr = x0 + xr;

  const f32x4* __restrict__ imgv = (const f32x4*)img;
  const f32x4* p00 = imgv + (size_t)(rt * IW + cl) * C4G + lane;
  const f32x4* p01 = imgv + (size_t)(rt * IW + cr) * C4G + lane;
  const f32x4* p10 = imgv + (size_t)(rb * IW + cl) * C4G + lane;
  const f32x4* p11 = imgv + (size_t)(rb * IW + cr) * C4G + lane;

  // 8 loads in flight per wave
  f32x4 a00 = p00[0], b00 = p00[64];
  f32x4 a01 = p01[0], b01 = p01[64];
  f32x4 a10 = p10[0], b10 = p10[64];
  f32x4 a11 = p11[0], b11 = p11[64];

  f32x4 wxv = wx;
  f32x4 wyv = wy;

  f32x4 atop = a00 + wxv * (a01 - a00);
  f32x4 abot = a10 + wxv * (a11 - a10);
  f32x4 ra = atop + wyv * (abot - atop);

  f32x4 btop = b00 + wxv * (b01 - b00);
  f32x4 bbot = b10 + wxv * (b11 - b10);
  f32x4 rbv = btop + wyv * (bbot - btop);

  // Output is never re-read: non-temporal stores keep the 401 MB write
  // stream from evicting image lines out of L2.
  f32x4* outv = (f32x4*)out + (size_t)pid * C4G + lane;
  __builtin_nontemporal_store(ra, outv);
  __builtin_nontemporal_store(rbv, outv + 64);
}

extern "C" void kernel_launch(void* const* d_in, const int* in_sizes, int n_in,
                              void* d_out, int out_size, void* d_ws, size_t ws_size,
                              hipStream_t stream) {
  const float* img = (const float*)d_in[0];
  const int* rois = (const int*)d_in[1];
  float* out = (float*)d_out;

  int N = in_sizes[1] / 4;   // rois is [N,4]
  int npix = N * PH * PW;    // output pixels == waves
  int blocks = (npix + 3) / 4;
  // Swizzle needs blocks % 8 == 0 for a bijective remap: npix = N*196,
  // blocks = N*49, so N % 8 == 0 suffices (N=1000 -> 49000 blocks).
  int swizzle = (N % 8 == 0) ? 1 : 0;
  roi_pool_kernel<<<blocks, 256, 0, stream>>>(img, rois, out, npix, swizzle);
}

// Round 4
// 423.167 us; speedup vs baseline: 1.2030x; 1.0816x over previous
//
#include <hip/hip_runtime.h>

#define PH 14
#define PW 14
#define CC 512
#define IW 128
#define C4G (CC / 4)  // 128 float4 channel groups per pixel

typedef float f32x4 __attribute__((ext_vector_type(4)));

// Pre-pass: bin ROIs into 64 spatial cells (8x8 grid of 16x16-px cells, by
// ROI center, Morton-ordered so consecutive cells are spatial neighbors),
// counting-sort into perm[]. One block, ~us.
__global__ __launch_bounds__(256) void roi_sort_kernel(
    const int* __restrict__ rois, int* __restrict__ perm, int n) {
  __shared__ int hist[64];
  __shared__ int base[64];
  __shared__ int cnt[64];
  int t = threadIdx.x;
  if (t < 64) { hist[t] = 0; cnt[t] = 0; }
  __syncthreads();
  for (int r = t; r < n; r += 256) {
    int xc = min((rois[4 * r + 0] + rois[4 * r + 2]) >> 5, 7);
    int yc = min((rois[4 * r + 1] + rois[4 * r + 3]) >> 5, 7);
    // Morton interleave of 3-bit (yc, xc)
    int key = (xc & 1) | ((yc & 1) << 1) | ((xc & 2) << 1) | ((yc & 2) << 2) |
              ((xc & 4) << 2) | ((yc & 4) << 3);
    atomicAdd(&hist[key], 1);
  }
  __syncthreads();
  if (t == 0) {
    int s = 0;
    for (int i = 0; i < 64; i++) { base[i] = s; s += hist[i]; }
  }
  __syncthreads();
  for (int r = t; r < n; r += 256) {
    int xc = min((rois[4 * r + 0] + rois[4 * r + 2]) >> 5, 7);
    int yc = min((rois[4 * r + 1] + rois[4 * r + 3]) >> 5, 7);
    int key = (xc & 1) | ((yc & 1) << 1) | ((xc & 2) << 1) | ((yc & 2) << 2) |
              ((xc & 4) << 2) | ((yc & 4) << 3);
    int pos = base[key] + atomicAdd(&cnt[key], 1);
    perm[pos] = r;
  }
}

// One wave (64 lanes) = one output pixel (roi, py, px); each lane handles
// 2 float4 channel groups (lane, lane+64). 4 waves/block, 49 blocks/ROI.
//
// Scheduling (mode 2): XCD x (HW: XCD = blockIdx % 8) processes the
// contiguous sorted chunk perm[x*nroi8 .. x*nroi8+nroi8), so consecutively
// executed ROIs on an XCD overlap in the image and the ~17x inter-ROI byte
// reuse (1000 ROI footprints over a 33.5 MB image) is captured by the
// private 4 MB L2 instead of re-missing to L3/HBM per ROI.
__global__ __launch_bounds__(256) void roi_pool_kernel(
    const float* __restrict__ img, const int* __restrict__ rois,
    const int* __restrict__ perm, float* __restrict__ out,
    int npix, int mode, int nroi8) {
  int w = threadIdx.x >> 6;  // wave within block
  int wid;
  if (mode) {
    int bid = blockIdx.x;
    int x   = bid & 7;    // target XCD
    int seq = bid >> 3;   // dense sequence within this XCD
    int rg  = seq / 49;   // ROI slot on this XCD
    int k   = seq % 49;   // block within ROI (4 px each)
    int r   = (mode == 2) ? perm[x * nroi8 + rg]  // spatially sorted
                          : rg * 8 + x;           // plain chunking
    wid = r * (PH * PW) + k * 4 + w;
  } else {
    wid = blockIdx.x * 4 + w;
  }
  if (wid >= npix) return;                   // wave-uniform branch
  int pid = __builtin_amdgcn_readfirstlane(wid);
  int lane = threadIdx.x & 63;

  int px = pid % PW;
  int tmp = pid / PW;
  int py = tmp % PH;
  int n = tmp / PH;

  // scalar (s_load_dwordx4) ROI fetch
  int x0 = rois[n * 4 + 0];
  int y0 = rois[n * 4 + 1];
  int x1 = rois[n * 4 + 2];
  int y1 = rois[n * 4 + 3];
  int in_w = x1 - x0 + 1;
  int in_h = y1 - y0 + 1;

  // Match reference float op order exactly: scale = in/out, then idx*scale.
  float scale_y = (float)in_h / (float)PH;
  float scale_x = (float)in_w / (float)PW;
  float sy = (float)py * scale_y;
  float sx = (float)px * scale_x;
  int yt = (int)floorf(sy);
  int xt = (int)floorf(sx);
  int yb = min(yt + 1, in_h - 1);
  int xr = min(xt + 1, in_w - 1);
  float wy = sy - (float)yt;
  float wx = sx - (float)xt;

  int rt = y0 + yt, rb = y0 + yb;
  int cl = x0 + xt, cr = x0 + xr;

  const f32x4* __restrict__ imgv = (const f32x4*)img;
  const f32x4* p00 = imgv + (size_t)(rt * IW + cl) * C4G + lane;
  const f32x4* p01 = imgv + (size_t)(rt * IW + cr) * C4G + lane;
  const f32x4* p10 = imgv + (size_t)(rb * IW + cl) * C4G + lane;
  const f32x4* p11 = imgv + (size_t)(rb * IW + cr) * C4G + lane;

  // 8 loads in flight per wave
  f32x4 a00 = p00[0], b00 = p00[64];
  f32x4 a01 = p01[0], b01 = p01[64];
  f32x4 a10 = p10[0], b10 = p10[64];
  f32x4 a11 = p11[0], b11 = p11[64];

  f32x4 wxv = wx;
  f32x4 wyv = wy;

  f32x4 atop = a00 + wxv * (a01 - a00);
  f32x4 abot = a10 + wxv * (a11 - a10);
  f32x4 ra = atop + wyv * (abot - atop);

  f32x4 btop = b00 + wxv * (b01 - b00);
  f32x4 bbot = b10 + wxv * (b11 - b10);
  f32x4 rbv = btop + wyv * (bbot - btop);

  // Output is never re-read: non-temporal stores keep the 401 MB write
  // stream from evicting image lines out of L2.
  f32x4* outv = (f32x4*)out + (size_t)pid * C4G + lane;
  __builtin_nontemporal_store(ra, outv);
  __builtin_nontemporal_store(rbv, outv + 64);
}

extern "C" void kernel_launch(void* const* d_in, const int* in_sizes, int n_in,
                              void* d_out, int out_size, void* d_ws, size_t ws_size,
                              hipStream_t stream) {
  const float* img = (const float*)d_in[0];
  const int* rois = (const int*)d_in[1];
  float* out = (float*)d_out;

  int N = in_sizes[1] / 4;   // rois is [N,4]
  int npix = N * PH * PW;    // output pixels == waves
  int blocks = (npix + 3) / 4;

  // mode 2 (sorted spatial chunks) needs N % 8 == 0 and workspace for perm.
  int* perm = (int*)d_ws;
  int mode = 0;
  if (N > 0 && (N % 8) == 0) {
    mode = (d_ws != nullptr && ws_size >= (size_t)N * sizeof(int)) ? 2 : 1;
  }
  if (mode == 2) {
    roi_sort_kernel<<<1, 256, 0, stream>>>(rois, perm, N);
  }
  roi_pool_kernel<<<blocks, 256, 0, stream>>>(img, rois, perm, out, npix,
                                              mode, N / 8);
}